// Round 1
// baseline (4412.803 us; speedup 1.0000x reference)
//
#include <hip/hip_runtime.h>

#define B_   128
#define T_   128
#define DIN  64
#define H_   1024
#define NBLK 256
#define NTHR 256

typedef _Float16 f16;
typedef _Float16 half8 __attribute__((ext_vector_type(8)));
typedef float float4v __attribute__((ext_vector_type(4)));

// LDS layout (dynamic shared):
//  W1 : f16[16][1096]  (16 gate-rows x (1024 h1 + 64 x) K, pad 8)  35072 B
//  W2 : f16[16][2056]  (16 gate-rows x (1024 h1 + 1024 h2), pad 8) 65792 B
//  Sg : float[128][17] gate-transpose scratch                       8704 B
//  c1 : float[128*4], c2 : float[128*4]                             4096 B
//  bs1: float[16], bs2: float[16]                                    128 B
#define OFF_W2 35072
#define OFF_SG 100864
#define OFF_C1 109568
#define OFF_C2 111616
#define OFF_B1 113664
#define OFF_B2 113728
#define SMEM_BYTES 113792

struct Params {
  const float *x, *Wih1, *Whh1, *bih1, *bhh1, *Wih2, *Whh2, *bih2, *bhh2,
              *Wlin, *blin, *Whio, *bhio;
  const int* fut;
  float* out;
  f16 *x16, *h1a, *h1b, *h2a, *h2b, *ob;
  unsigned *arrive, *rel;
};

__device__ __forceinline__ float sigm(float v) { return 1.f / (1.f + __expf(-v)); }
__device__ __forceinline__ float tanh_(float v) { return 2.f / (1.f + __expf(-2.f * v)) - 1.f; }

// Distributed grid barrier: per-block arrival slots + single release word.
// Agent-scope release/acquire -> buffer_wbl2 / buffer_inv handle cross-XCD L2.
// Spin-until-equal: 0xAAAAAAAA ws poison can never equal ph (ph starts at 1,
// increments ~133 times per launch; ws re-poisoned before every launch).
__device__ __forceinline__ void grid_sync(unsigned* arrive, unsigned* rel, unsigned ph) {
  __syncthreads();  // drains this block's vmcnt: all global stores in L2
  const int tid = threadIdx.x, bid = blockIdx.x;
  if (bid == 0) {
    if (tid > 0) {  // thread t polls block t (blocks 1..255)
      while (__hip_atomic_load(&arrive[tid], __ATOMIC_RELAXED, __HIP_MEMORY_SCOPE_AGENT) != ph)
        __builtin_amdgcn_s_sleep(1);
    }
    __syncthreads();
    if (tid == 0)
      __hip_atomic_store(rel, ph, __ATOMIC_RELEASE, __HIP_MEMORY_SCOPE_AGENT);
  } else {
    if (tid == 0) {
      __hip_atomic_store(&arrive[bid], ph, __ATOMIC_RELEASE, __HIP_MEMORY_SCOPE_AGENT);
      while (__hip_atomic_load(rel, __ATOMIC_RELAXED, __HIP_MEMORY_SCOPE_AGENT) != ph)
        __builtin_amdgcn_s_sleep(1);
    }
  }
  __syncthreads();
  __builtin_amdgcn_fence(__ATOMIC_ACQUIRE, "agent");  // invalidate stale L1/L2
}

__global__ void __launch_bounds__(NTHR, 1) lstm_k(Params p) {
  extern __shared__ char smem[];
  f16*   W1  = (f16*)(smem);
  f16*   W2  = (f16*)(smem + OFF_W2);
  float* Sg  = (float*)(smem + OFF_SG);
  float* c1  = (float*)(smem + OFF_C1);
  float* c2  = (float*)(smem + OFF_C2);
  float* bs1 = (float*)(smem + OFF_B1);
  float* bs2 = (float*)(smem + OFF_B2);

  const int tid = threadIdx.x, bid = blockIdx.x;
  const int hb  = bid * 4;          // this block's 4 h-columns (both layers)
  const int fut = p.fut[0];

  // ---------------- preamble: weights -> LDS f16, x -> f16, zero states ----
  for (int idx = tid; idx < 16 * 1088; idx += NTHR) {
    int n = idx / 1088, k = idx - n * 1088;
    int r = (n >> 2) * H_ + hb + (n & 3);     // gate-major packed row
    float v = (k < H_) ? p.Whh1[r * H_ + k] : p.Wih1[r * DIN + k - H_];
    W1[n * 1096 + k] = (f16)v;
  }
  for (int idx = tid; idx < 16 * 2048; idx += NTHR) {
    int n = idx >> 11, k = idx & 2047;
    int r = (n >> 2) * H_ + hb + (n & 3);
    float v = (k < H_) ? p.Wih2[r * H_ + k] : p.Whh2[r * H_ + k - H_];
    W2[n * 2056 + k] = (f16)v;
  }
  if (tid < 16) {
    int r = (tid >> 2) * H_ + hb + (tid & 3);
    bs1[tid] = p.bih1[r] + p.bhh1[r];
    bs2[tid] = p.bih2[r] + p.bhh2[r];
  }
  for (int i = tid; i < 512; i += NTHR) { c1[i] = 0.f; c2[i] = 0.f; }
  for (int i = bid * NTHR + tid; i < B_ * T_ * DIN; i += NBLK * NTHR)
    p.x16[i] = (f16)p.x[i];
  for (int i = bid * NTHR + tid; i < B_ * H_; i += NBLK * NTHR) {
    p.h1a[i] = (f16)0.f; p.h1b[i] = (f16)0.f;
    p.h2a[i] = (f16)0.f; p.h2b[i] = (f16)0.f;
  }

  unsigned ph = 0;
  unsigned* arr = p.arrive; unsigned* rel = p.rel;
  auto gsync = [&]() { ++ph; grid_sync(arr, rel, ph); };
  gsync();  // preamble visible everywhere

  // ---------------- per-wave MFMA geometry ---------------------------------
  const int lane = tid & 63, wv = tid >> 6;
  const int col = lane & 15, quad = lane >> 4;
  const int m0 = wv * 32 + col;        // A row (batch) for m-tile 2*wv
  const int m1 = wv * 32 + 16 + col;   // A row for m-tile 2*wv+1
  const int ko = quad * 8;             // k offset within 32-chunk
  const float b1v = bs1[col], b2v = bs2[col];
  const f16* W1p = W1 + col * 1096 + ko;
  const f16* W2p = W2 + col * 2056 + ko;

  f16 *h1c = p.h1a, *h1n = p.h1b, *h2c = p.h2a, *h2n = p.h2b;

  // one fused phase: gates1(t+1) [l1] and gates2(t) [l2], both keyed on h1c
  auto phase = [&](bool l1, bool l2, const f16* xp, int xstr) {
    float4v a10 = {b1v, b1v, b1v, b1v}, a11 = a10;
    float4v a20 = {b2v, b2v, b2v, b2v}, a21 = a20;
    const f16* A0 = h1c + m0 * H_ + ko;
    const f16* A1 = h1c + m1 * H_ + ko;
    if (l1 && l2) {
      #pragma unroll 4
      for (int kc = 0; kc < 32; ++kc) {
        half8 a0 = *(const half8*)(A0 + kc * 32);
        half8 a1 = *(const half8*)(A1 + kc * 32);
        half8 b1 = *(const half8*)(W1p + kc * 32);
        half8 b2 = *(const half8*)(W2p + kc * 32);
        a10 = __builtin_amdgcn_mfma_f32_16x16x32_f16(a0, b1, a10, 0, 0, 0);
        a11 = __builtin_amdgcn_mfma_f32_16x16x32_f16(a1, b1, a11, 0, 0, 0);
        a20 = __builtin_amdgcn_mfma_f32_16x16x32_f16(a0, b2, a20, 0, 0, 0);
        a21 = __builtin_amdgcn_mfma_f32_16x16x32_f16(a1, b2, a21, 0, 0, 0);
      }
    } else if (l1) {
      #pragma unroll 4
      for (int kc = 0; kc < 32; ++kc) {
        half8 a0 = *(const half8*)(A0 + kc * 32);
        half8 a1 = *(const half8*)(A1 + kc * 32);
        half8 b1 = *(const half8*)(W1p + kc * 32);
        a10 = __builtin_amdgcn_mfma_f32_16x16x32_f16(a0, b1, a10, 0, 0, 0);
        a11 = __builtin_amdgcn_mfma_f32_16x16x32_f16(a1, b1, a11, 0, 0, 0);
      }
    } else {
      #pragma unroll 4
      for (int kc = 0; kc < 32; ++kc) {
        half8 a0 = *(const half8*)(A0 + kc * 32);
        half8 a1 = *(const half8*)(A1 + kc * 32);
        half8 b2 = *(const half8*)(W2p + kc * 32);
        a20 = __builtin_amdgcn_mfma_f32_16x16x32_f16(a0, b2, a20, 0, 0, 0);
        a21 = __builtin_amdgcn_mfma_f32_16x16x32_f16(a1, b2, a21, 0, 0, 0);
      }
    }
    if (l2) {  // h2 half of K for gates2
      const f16* C0 = h2c + m0 * H_ + ko;
      const f16* C1r = h2c + m1 * H_ + ko;
      #pragma unroll 4
      for (int kc = 0; kc < 32; ++kc) {
        half8 a0 = *(const half8*)(C0 + kc * 32);
        half8 a1 = *(const half8*)(C1r + kc * 32);
        half8 b2 = *(const half8*)(W2p + 1024 + kc * 32);
        a20 = __builtin_amdgcn_mfma_f32_16x16x32_f16(a0, b2, a20, 0, 0, 0);
        a21 = __builtin_amdgcn_mfma_f32_16x16x32_f16(a1, b2, a21, 0, 0, 0);
      }
    }
    if (l1) {  // x (or fed-back output) part of K for gates1
      #pragma unroll
      for (int kx = 0; kx < 2; ++kx) {
        half8 a0 = *(const half8*)(xp + m0 * xstr + kx * 32 + ko);
        half8 a1 = *(const half8*)(xp + m1 * xstr + kx * 32 + ko);
        half8 b1 = *(const half8*)(W1p + 1024 + kx * 32);
        a10 = __builtin_amdgcn_mfma_f32_16x16x32_f16(a0, b1, a10, 0, 0, 0);
        a11 = __builtin_amdgcn_mfma_f32_16x16x32_f16(a1, b1, a11, 0, 0, 0);
      }
    }
    // ---- epilogues: transpose gates via LDS, LSTM pointwise, write h ----
    if (l1) {
      __syncthreads();
      #pragma unroll
      for (int r = 0; r < 4; ++r) {
        Sg[(wv * 32 + quad * 4 + r) * 17 + col]      = a10[r];
        Sg[(wv * 32 + 16 + quad * 4 + r) * 17 + col] = a11[r];
      }
      __syncthreads();
      for (int it = tid; it < 512; it += NTHR) {
        int m = it >> 2, cc = it & 3;
        float gi = Sg[m * 17 + cc],     gf = Sg[m * 17 + 4 + cc];
        float gg = Sg[m * 17 + 8 + cc], go = Sg[m * 17 + 12 + cc];
        float cn = sigm(gf) * c1[it] + sigm(gi) * tanh_(gg);
        c1[it] = cn;
        h1n[m * H_ + hb + cc] = (f16)(sigm(go) * tanh_(cn));
      }
    }
    if (l2) {
      __syncthreads();
      #pragma unroll
      for (int r = 0; r < 4; ++r) {
        Sg[(wv * 32 + quad * 4 + r) * 17 + col]      = a20[r];
        Sg[(wv * 32 + 16 + quad * 4 + r) * 17 + col] = a21[r];
      }
      __syncthreads();
      for (int it = tid; it < 512; it += NTHR) {
        int m = it >> 2, cc = it & 3;
        float gi = Sg[m * 17 + cc],     gf = Sg[m * 17 + 4 + cc];
        float gg = Sg[m * 17 + 8 + cc], go = Sg[m * 17 + 12 + cc];
        float cn = sigm(gf) * c2[it] + sigm(gi) * tanh_(gg);
        c2[it] = cn;
        h2n[m * H_ + hb + cc] = (f16)(sigm(go) * tanh_(cn));
      }
    }
  };

  // small projection: out[m][j] = h2 . W[j] + b[j]  (fp32 weights)
  auto out_phase = [&](const float* W, const float* bv, bool wout) {
    int j = bid & 63, mg = bid >> 6;
    int rid = tid >> 3, ks = tid & 7;
    int m = mg * 32 + rid;
    const f16* hr = h2c + m * H_ + ks * 128;
    const float* wr = W + j * H_ + ks * 128;
    float s = 0.f;
    #pragma unroll 8
    for (int k = 0; k < 128; ++k) s += (float)hr[k] * wr[k];
    s += __shfl_down(s, 4, 8);
    s += __shfl_down(s, 2, 8);
    s += __shfl_down(s, 1, 8);
    if (ks == 0) {
      float v = s + bv[j];
      p.ob[m * 64 + j] = (f16)v;
      if (wout) p.out[m * 64 + j] = v;
    }
  };

  // ---------------- time loop: 129 fused phases ----------------------------
  for (int t = -1; t < T_; ++t) {
    bool l1 = (t + 1 < T_), l2 = (t >= 0);
    phase(l1, l2, p.x16 + (t + 1) * DIN, T_ * DIN);
    gsync();
    if (l1) { f16* tm = h1c; h1c = h1n; h1n = tm; }
    if (l2) { f16* tm = h2c; h2c = h2n; h2n = tm; }
  }
  // scan output projection (is the final answer if future==0)
  out_phase(p.Wlin, p.blin, fut == 0);
  gsync();
  // future steps (reference: future=1)
  for (int f = 0; f < fut; ++f) {
    phase(true, false, p.ob, 64);
    gsync();
    { f16* tm = h1c; h1c = h1n; h1n = tm; }
    phase(false, true, p.ob, 64);
    gsync();
    { f16* tm = h2c; h2c = h2n; h2n = tm; }
    out_phase(p.Whio, p.bhio, f == fut - 1);
    gsync();
  }
}

extern "C" void kernel_launch(void* const* d_in, const int* in_sizes, int n_in,
                              void* d_out, int out_size, void* d_ws, size_t ws_size,
                              hipStream_t stream) {
  char* w = (char*)d_ws;
  auto carve = [&](size_t n) { char* r = w; w += (n + 255) & ~(size_t)255; return r; };

  Params p;
  p.x    = (const float*)d_in[0];
  p.Wih1 = (const float*)d_in[1];
  p.Whh1 = (const float*)d_in[2];
  p.bih1 = (const float*)d_in[3];
  p.bhh1 = (const float*)d_in[4];
  p.Wih2 = (const float*)d_in[5];
  p.Whh2 = (const float*)d_in[6];
  p.bih2 = (const float*)d_in[7];
  p.bhh2 = (const float*)d_in[8];
  p.Wlin = (const float*)d_in[9];
  p.blin = (const float*)d_in[10];
  p.Whio = (const float*)d_in[11];
  p.bhio = (const float*)d_in[12];
  p.fut  = (const int*)d_in[13];
  p.out  = (float*)d_out;

  p.x16 = (f16*)carve((size_t)B_ * T_ * DIN * 2);
  p.h1a = (f16*)carve((size_t)B_ * H_ * 2);
  p.h1b = (f16*)carve((size_t)B_ * H_ * 2);
  p.h2a = (f16*)carve((size_t)B_ * H_ * 2);
  p.h2b = (f16*)carve((size_t)B_ * H_ * 2);
  p.ob  = (f16*)carve((size_t)B_ * 64 * 2);
  p.arrive = (unsigned*)carve(NBLK * sizeof(unsigned));
  p.rel    = (unsigned*)carve(256);

  (void)hipFuncSetAttribute((const void*)lstm_k,
                            hipFuncAttributeMaxDynamicSharedMemorySize, SMEM_BYTES);
  void* args[] = { &p };
  (void)hipLaunchCooperativeKernel((void*)lstm_k, dim3(NBLK), dim3(NTHR),
                                   args, SMEM_BYTES, stream);
}

// Round 2
// 3039.355 us; speedup vs baseline: 1.4519x; 1.4519x over previous
//
#include <hip/hip_runtime.h>

#define B_   128
#define T_   128
#define DIN  64
#define H_   1024
#define NBLK 256
#define NTHR 512

typedef _Float16 f16;
typedef _Float16 half8 __attribute__((ext_vector_type(8)));
typedef float float4v __attribute__((ext_vector_type(4)));

// LDS layout (dynamic shared):
//  W1 : f16[16][1096]  (16 gate-rows x (1024 h1 + 64 x) K, pad 8)  35072 B
//  W2 : f16[16][2056]  (16 gate-rows x (1024 h1 + 1024 h2), pad 8) 65792 B
//  Sg : float[128][17] gate-transpose scratch                       8704 B
//  c1 : float[128*4], c2 : float[128*4]                             4096 B
//  bs1: float[16], bs2: float[16]                                    128 B
#define OFF_W2 35072
#define OFF_SG 100864
#define OFF_C1 109568
#define OFF_C2 111616
#define OFF_B1 113664
#define OFF_B2 113728
#define SMEM_BYTES 113792

struct Params {
  const float *x, *Wih1, *Whh1, *bih1, *bhh1, *Wih2, *Whh2, *bih2, *bhh2,
              *Wlin, *blin, *Whio, *bhio;
  const int* fut;
  float* out;
  f16 *x16, *h1a, *h1b, *h2a, *h2b, *ob;
  unsigned *arrive, *rel;
  unsigned *S;   // [0..15] xtick, [16..31] xflag, [32] central, [34..49] xtot
};

__device__ __forceinline__ float sigm(float v) { return 1.f / (1.f + __expf(-v)); }
__device__ __forceinline__ float tanh_(float v) { return 2.f / (1.f + __expf(-2.f * v)) - 1.f; }

__device__ __forceinline__ unsigned get_xcc() {
  unsigned x;
  asm volatile("s_getreg_b32 %0, hwreg(HW_REG_XCC_ID)" : "=s"(x));
  return x & 15u;
}

// ---- slow barrier (preamble only): full fences, known-correct from R1 ------
__device__ __forceinline__ void grid_sync(unsigned* arrive, unsigned* rel, unsigned ph) {
  __syncthreads();
  const int tid = threadIdx.x, bid = blockIdx.x;
  if (bid == 0) {
    if (tid > 0 && tid < NBLK) {
      while (__hip_atomic_load(&arrive[tid], __ATOMIC_RELAXED, __HIP_MEMORY_SCOPE_AGENT) != ph)
        __builtin_amdgcn_s_sleep(1);
    }
    __syncthreads();
    if (tid == 0)
      __hip_atomic_store(rel, ph, __ATOMIC_RELEASE, __HIP_MEMORY_SCOPE_AGENT);
  } else {
    if (tid == 0) {
      __hip_atomic_store(&arrive[bid], ph, __ATOMIC_RELEASE, __HIP_MEMORY_SCOPE_AGENT);
      while (__hip_atomic_load(rel, __ATOMIC_RELAXED, __HIP_MEMORY_SCOPE_AGENT) != ph)
        __builtin_amdgcn_s_sleep(1);
    }
  }
  __syncthreads();
  __builtin_amdgcn_fence(__ATOMIC_ACQUIRE, "agent");
}

// ---- fast barrier: ONE buffer_wbl2 + ONE buffer_inv (L2) per XCD per phase.
// Others only invalidate their CU's L1 (buffer_inv sc0). Monotonic tickets;
// spin-until-equal on phase numbers (0xAA poison never matches).
__device__ __forceinline__ void fast_sync(unsigned* S, unsigned x, unsigned xtotal,
                                          unsigned nxcd, unsigned ph) {
  __syncthreads();  // s_waitcnt vmcnt(0): this block's stores are in L2
  if (threadIdx.x == 0) {
    unsigned t = __hip_atomic_fetch_add(&S[x], 1u, __ATOMIC_RELAXED, __HIP_MEMORY_SCOPE_AGENT);
    if ((t + 1u) % xtotal == 0u) {            // last block of this XCD
      asm volatile("buffer_wbl2 sc1\n\ts_waitcnt vmcnt(0)" ::: "memory");
      unsigned c = __hip_atomic_fetch_add(&S[32], 1u, __ATOMIC_RELAXED, __HIP_MEMORY_SCOPE_AGENT);
      if ((c + 1u) % nxcd == 0u)              // last XCD globally -> release
        __hip_atomic_store(&S[33], ph, __ATOMIC_RELAXED, __HIP_MEMORY_SCOPE_AGENT);
    }
    while (__hip_atomic_load(&S[33], __ATOMIC_RELAXED, __HIP_MEMORY_SCOPE_AGENT) != ph)
      __builtin_amdgcn_s_sleep(1);
    if (t % xtotal == 0u) {                   // first block of this XCD = leader
      asm volatile("buffer_inv sc1\n\ts_waitcnt vmcnt(0)" ::: "memory");
      __hip_atomic_store(&S[16 + x], ph, __ATOMIC_RELAXED, __HIP_MEMORY_SCOPE_AGENT);
    } else {
      while (__hip_atomic_load(&S[16 + x], __ATOMIC_RELAXED, __HIP_MEMORY_SCOPE_AGENT) != ph)
        __builtin_amdgcn_s_sleep(1);
      asm volatile("buffer_inv sc0\n\ts_waitcnt vmcnt(0)" ::: "memory");  // L1 only
    }
  }
  __syncthreads();
}

__global__ void __launch_bounds__(NTHR, 1) lstm_k(Params p) {
  extern __shared__ char smem[];
  f16*   W1  = (f16*)(smem);
  f16*   W2  = (f16*)(smem + OFF_W2);
  float* Sg  = (float*)(smem + OFF_SG);
  float* c1  = (float*)(smem + OFF_C1);
  float* c2  = (float*)(smem + OFF_C2);
  float* bs1 = (float*)(smem + OFF_B1);
  float* bs2 = (float*)(smem + OFF_B2);

  const int tid = threadIdx.x, bid = blockIdx.x;
  const int hb  = bid * 4;
  const int fut = p.fut[0];
  const unsigned xcc = get_xcc();
  unsigned* S = p.S;

  // zero fast-barrier state (block 0, before the first slow barrier)
  if (bid == 0) {
    if (tid < 16) {
      __hip_atomic_store(&S[tid], 0u, __ATOMIC_RELAXED, __HIP_MEMORY_SCOPE_AGENT);       // xtick
      __hip_atomic_store(&S[34 + tid], 0u, __ATOMIC_RELAXED, __HIP_MEMORY_SCOPE_AGENT);  // xtot
    }
    if (tid == 0)
      __hip_atomic_store(&S[32], 0u, __ATOMIC_RELAXED, __HIP_MEMORY_SCOPE_AGENT);        // central
  }

  // ---------------- preamble: weights -> LDS f16, x -> f16, zero states ----
  for (int idx = tid; idx < 16 * 1088; idx += NTHR) {
    int n = idx / 1088, k = idx - n * 1088;
    int r = (n >> 2) * H_ + hb + (n & 3);
    float v = (k < H_) ? p.Whh1[r * H_ + k] : p.Wih1[r * DIN + k - H_];
    W1[n * 1096 + k] = (f16)v;
  }
  for (int idx = tid; idx < 16 * 2048; idx += NTHR) {
    int n = idx >> 11, k = idx & 2047;
    int r = (n >> 2) * H_ + hb + (n & 3);
    float v = (k < H_) ? p.Wih2[r * H_ + k] : p.Whh2[r * H_ + k - H_];
    W2[n * 2056 + k] = (f16)v;
  }
  if (tid < 16) {
    int r = (tid >> 2) * H_ + hb + (tid & 3);
    bs1[tid] = p.bih1[r] + p.bhh1[r];
    bs2[tid] = p.bih2[r] + p.bhh2[r];
  }
  for (int i = tid; i < 512; i += NTHR) { c1[i] = 0.f; c2[i] = 0.f; }
  for (int i = bid * NTHR + tid; i < B_ * T_ * DIN; i += NBLK * NTHR)
    p.x16[i] = (f16)p.x[i];
  for (int i = bid * NTHR + tid; i < B_ * H_; i += NBLK * NTHR) {
    p.h1a[i] = (f16)0.f; p.h1b[i] = (f16)0.f;
    p.h2a[i] = (f16)0.f; p.h2b[i] = (f16)0.f;
  }

  unsigned ph = 1;
  grid_sync(p.arrive, p.rel, ph);            // preamble + S-zero visible
  if (tid == 0)
    __hip_atomic_fetch_add(&S[34 + xcc], 1u, __ATOMIC_RELAXED, __HIP_MEMORY_SCOPE_AGENT);
  ++ph;
  grid_sync(p.arrive, p.rel, ph);            // xtot counts final

  unsigned xtotal = __hip_atomic_load(&S[34 + xcc], __ATOMIC_RELAXED, __HIP_MEMORY_SCOPE_AGENT);
  unsigned nxcd = 0;
  for (int i = 0; i < 16; ++i)
    nxcd += (__hip_atomic_load(&S[34 + i], __ATOMIC_RELAXED, __HIP_MEMORY_SCOPE_AGENT) != 0u);

  auto gsync = [&]() { ++ph; fast_sync(S, xcc, xtotal, nxcd, ph); };

  // ---------------- per-wave MFMA geometry: 8 waves, one 16-row m-tile each
  const int lane = tid & 63, wv = tid >> 6;
  const int col = lane & 15, quad = lane >> 4;
  const int m   = wv * 16 + col;       // A row (batch)
  const int ko  = quad * 8;            // k offset within 32-chunk
  const float b1v = bs1[col], b2v = bs2[col];
  const f16* W1p = W1 + col * 1096 + ko;
  const f16* W2p = W2 + col * 2056 + ko;

  f16 *h1c = p.h1a, *h1n = p.h1b, *h2c = p.h2a, *h2n = p.h2b;

  // fused phase: gates1(t+1) [l1] and gates2(t) [l2], both keyed on h1c
  auto phase = [&](bool l1, bool l2, const f16* xp, int xstr) {
    float4v a1 = {b1v, b1v, b1v, b1v};
    float4v a2 = {b2v, b2v, b2v, b2v};
    const f16* A0 = h1c + m * H_ + ko;
    if (l1 && l2) {
      #pragma unroll 8
      for (int kc = 0; kc < 32; ++kc) {
        half8 a  = *(const half8*)(A0 + kc * 32);
        half8 w1 = *(const half8*)(W1p + kc * 32);
        half8 w2 = *(const half8*)(W2p + kc * 32);
        a1 = __builtin_amdgcn_mfma_f32_16x16x32_f16(a, w1, a1, 0, 0, 0);
        a2 = __builtin_amdgcn_mfma_f32_16x16x32_f16(a, w2, a2, 0, 0, 0);
      }
    } else if (l1) {
      #pragma unroll 8
      for (int kc = 0; kc < 32; ++kc) {
        half8 a  = *(const half8*)(A0 + kc * 32);
        half8 w1 = *(const half8*)(W1p + kc * 32);
        a1 = __builtin_amdgcn_mfma_f32_16x16x32_f16(a, w1, a1, 0, 0, 0);
      }
    } else {
      #pragma unroll 8
      for (int kc = 0; kc < 32; ++kc) {
        half8 a  = *(const half8*)(A0 + kc * 32);
        half8 w2 = *(const half8*)(W2p + kc * 32);
        a2 = __builtin_amdgcn_mfma_f32_16x16x32_f16(a, w2, a2, 0, 0, 0);
      }
    }
    if (l2) {  // h2 half of K for gates2
      const f16* C0 = h2c + m * H_ + ko;
      #pragma unroll 8
      for (int kc = 0; kc < 32; ++kc) {
        half8 a  = *(const half8*)(C0 + kc * 32);
        half8 w2 = *(const half8*)(W2p + 1024 + kc * 32);
        a2 = __builtin_amdgcn_mfma_f32_16x16x32_f16(a, w2, a2, 0, 0, 0);
      }
    }
    if (l1) {  // x (or fed-back output) part of K for gates1
      #pragma unroll
      for (int kx = 0; kx < 2; ++kx) {
        half8 a  = *(const half8*)(xp + m * xstr + kx * 32 + ko);
        half8 w1 = *(const half8*)(W1p + 1024 + kx * 32);
        a1 = __builtin_amdgcn_mfma_f32_16x16x32_f16(a, w1, a1, 0, 0, 0);
      }
    }
    // ---- epilogues: transpose gates via LDS, LSTM pointwise, write h ----
    if (l1) {
      __syncthreads();
      #pragma unroll
      for (int r = 0; r < 4; ++r)
        Sg[(wv * 16 + quad * 4 + r) * 17 + col] = a1[r];
      __syncthreads();
      {
        int mm = tid >> 2, cc = tid & 3;
        float gi = Sg[mm * 17 + cc],     gf = Sg[mm * 17 + 4 + cc];
        float gg = Sg[mm * 17 + 8 + cc], go = Sg[mm * 17 + 12 + cc];
        float cn = sigm(gf) * c1[tid] + sigm(gi) * tanh_(gg);
        c1[tid] = cn;
        h1n[mm * H_ + hb + cc] = (f16)(sigm(go) * tanh_(cn));
      }
    }
    if (l2) {
      __syncthreads();
      #pragma unroll
      for (int r = 0; r < 4; ++r)
        Sg[(wv * 16 + quad * 4 + r) * 17 + col] = a2[r];
      __syncthreads();
      {
        int mm = tid >> 2, cc = tid & 3;
        float gi = Sg[mm * 17 + cc],     gf = Sg[mm * 17 + 4 + cc];
        float gg = Sg[mm * 17 + 8 + cc], go = Sg[mm * 17 + 12 + cc];
        float cn = sigm(gf) * c2[tid] + sigm(gi) * tanh_(gg);
        c2[tid] = cn;
        h2n[mm * H_ + hb + cc] = (f16)(sigm(go) * tanh_(cn));
      }
    }
  };

  // small projection: out[m][j] = h2 . W[j] + b[j]  (fp32 weights)
  auto out_phase = [&](const float* W, const float* bv, bool wout) {
    int j = bid & 63, mg = bid >> 6;
    int rid = tid >> 4, ks = tid & 15;
    int mrow = mg * 32 + rid;
    const f16* hr = h2c + mrow * H_ + ks * 64;
    const float* wr = W + j * H_ + ks * 64;
    float s = 0.f;
    #pragma unroll 8
    for (int k = 0; k < 64; ++k) s += (float)hr[k] * wr[k];
    s += __shfl_down(s, 8, 16);
    s += __shfl_down(s, 4, 16);
    s += __shfl_down(s, 2, 16);
    s += __shfl_down(s, 1, 16);
    if (ks == 0) {
      float v = s + bv[j];
      p.ob[mrow * 64 + j] = (f16)v;
      if (wout) p.out[mrow * 64 + j] = v;
    }
  };

  // ---------------- time loop: 129 fused phases ----------------------------
  for (int t = -1; t < T_; ++t) {
    bool l1 = (t + 1 < T_), l2 = (t >= 0);
    phase(l1, l2, p.x16 + (t + 1) * DIN, T_ * DIN);
    gsync();
    if (l1) { f16* tm = h1c; h1c = h1n; h1n = tm; }
    if (l2) { f16* tm = h2c; h2c = h2n; h2n = tm; }
  }
  out_phase(p.Wlin, p.blin, fut == 0);
  gsync();
  for (int f = 0; f < fut; ++f) {
    phase(true, false, p.ob, 64);
    gsync();
    { f16* tm = h1c; h1c = h1n; h1n = tm; }
    phase(false, true, p.ob, 64);
    gsync();
    { f16* tm = h2c; h2c = h2n; h2n = tm; }
    out_phase(p.Whio, p.bhio, f == fut - 1);
    gsync();
  }
}

extern "C" void kernel_launch(void* const* d_in, const int* in_sizes, int n_in,
                              void* d_out, int out_size, void* d_ws, size_t ws_size,
                              hipStream_t stream) {
  char* w = (char*)d_ws;
  auto carve = [&](size_t n) { char* r = w; w += (n + 255) & ~(size_t)255; return r; };

  Params p;
  p.x    = (const float*)d_in[0];
  p.Wih1 = (const float*)d_in[1];
  p.Whh1 = (const float*)d_in[2];
  p.bih1 = (const float*)d_in[3];
  p.bhh1 = (const float*)d_in[4];
  p.Wih2 = (const float*)d_in[5];
  p.Whh2 = (const float*)d_in[6];
  p.bih2 = (const float*)d_in[7];
  p.bhh2 = (const float*)d_in[8];
  p.Wlin = (const float*)d_in[9];
  p.blin = (const float*)d_in[10];
  p.Whio = (const float*)d_in[11];
  p.bhio = (const float*)d_in[12];
  p.fut  = (const int*)d_in[13];
  p.out  = (float*)d_out;

  p.x16 = (f16*)carve((size_t)B_ * T_ * DIN * 2);
  p.h1a = (f16*)carve((size_t)B_ * H_ * 2);
  p.h1b = (f16*)carve((size_t)B_ * H_ * 2);
  p.h2a = (f16*)carve((size_t)B_ * H_ * 2);
  p.h2b = (f16*)carve((size_t)B_ * H_ * 2);
  p.ob  = (f16*)carve((size_t)B_ * 64 * 2);
  p.arrive = (unsigned*)carve(NBLK * sizeof(unsigned));
  p.rel    = (unsigned*)carve(256);
  p.S      = (unsigned*)carve(64 * sizeof(unsigned));

  (void)hipFuncSetAttribute((const void*)lstm_k,
                            hipFuncAttributeMaxDynamicSharedMemorySize, SMEM_BYTES);
  void* args[] = { &p };
  (void)hipLaunchCooperativeKernel((void*)lstm_k, dim3(NBLK), dim3(NTHR),
                                   args, SMEM_BYTES, stream);
}